// Round 1
// baseline (1336.394 us; speedup 1.0000x reference)
//
#include <hip/hip_runtime.h>
#include <math.h>

#define NQ 10000
#define D 200          // dim_s == n
#define M_SLOTS 50
#define BATCH 64
#define LBERT 512
#define HBERT 768
#define BNROWS (BATCH*D)   // 12800

// ---------------- generic fp32 tiled GEMM: C = A * B^T (+bias)(+act) ----------
// A: row-major [M,K] (AKM=false) or k-major [K,M] (AKM=true), leading dim lda
// B: row-major [N,K], leading dim ldb
// ACT: 0 none, 1 sigmoid, 2 tanh, 3 relu.  ACCUM: C += result of this pass.
template<bool AKM, int ACT, bool ACCUM>
__global__ __launch_bounds__(256) void gemm_nt(
    const float* __restrict__ A, const float* __restrict__ Bm,
    const float* __restrict__ bias, float* __restrict__ C,
    int M, int N, int K, int lda, int ldb, int ldc,
    long sA, long sC)
{
    __shared__ float As[16][64];
    __shared__ float Bs[16][64];
    const int tid = threadIdx.x;
    const int tx = tid & 15, ty = tid >> 4;
    const int n0 = blockIdx.x * 64, m0 = blockIdx.y * 64;
    const float* Ab = A + (long)blockIdx.z * sA;
    float* Cb = C + (long)blockIdx.z * sC;

    float acc[4][4] = {{0.f}};
    for (int k0 = 0; k0 < K; k0 += 16) {
        float4 av = make_float4(0.f,0.f,0.f,0.f);
        float4 bv = make_float4(0.f,0.f,0.f,0.f);
        const int r4 = tid >> 2, q4 = tid & 3;
        if (AKM) {
            int kk = tid >> 4, mq = tid & 15;
            int m = m0 + mq*4, k = k0 + kk;
            if (k < K && m + 3 < M) av = *(const float4*)(Ab + (long)k*lda + m);
            As[kk][mq*4+0] = av.x; As[kk][mq*4+1] = av.y;
            As[kk][mq*4+2] = av.z; As[kk][mq*4+3] = av.w;
        } else {
            int m = m0 + r4, k = k0 + q4*4;
            if (m < M && k + 3 < K) av = *(const float4*)(Ab + (long)m*lda + k);
            As[q4*4+0][r4] = av.x; As[q4*4+1][r4] = av.y;
            As[q4*4+2][r4] = av.z; As[q4*4+3][r4] = av.w;
        }
        {
            int n = n0 + r4, k = k0 + q4*4;
            if (n < N && k + 3 < K) bv = *(const float4*)(Bm + (long)n*ldb + k);
            Bs[q4*4+0][r4] = bv.x; Bs[q4*4+1][r4] = bv.y;
            Bs[q4*4+2][r4] = bv.z; Bs[q4*4+3][r4] = bv.w;
        }
        __syncthreads();
        #pragma unroll
        for (int kk = 0; kk < 16; kk++) {
            float4 a4 = *(const float4*)&As[kk][ty*4];
            float4 b4 = *(const float4*)&Bs[kk][tx*4];
            acc[0][0] += a4.x*b4.x; acc[0][1] += a4.x*b4.y; acc[0][2] += a4.x*b4.z; acc[0][3] += a4.x*b4.w;
            acc[1][0] += a4.y*b4.x; acc[1][1] += a4.y*b4.y; acc[1][2] += a4.y*b4.z; acc[1][3] += a4.y*b4.w;
            acc[2][0] += a4.z*b4.x; acc[2][1] += a4.z*b4.y; acc[2][2] += a4.z*b4.z; acc[2][3] += a4.z*b4.w;
            acc[3][0] += a4.w*b4.x; acc[3][1] += a4.w*b4.y; acc[3][2] += a4.w*b4.z; acc[3][3] += a4.w*b4.w;
        }
        __syncthreads();
    }
    #pragma unroll
    for (int i = 0; i < 4; i++) {
        int m = m0 + ty*4 + i;
        if (m >= M) continue;
        #pragma unroll
        for (int j = 0; j < 4; j++) {
            int n = n0 + tx*4 + j;
            if (n >= N) continue;
            float v = acc[i][j];
            if (ACCUM) v += Cb[(long)m*ldc + n];
            if (bias != nullptr) v += bias[n];
            if (ACT == 1) v = 1.f/(1.f + __expf(-v));
            else if (ACT == 2) v = tanhf(v);
            else if (ACT == 3) v = fmaxf(v, 0.f);
            Cb[(long)m*ldc + n] = v;
        }
    }
}

// ---------------- gather k = k_emb[q], v = v_emb[q + NQ*r] --------------------
__global__ void gather_kernel(const int* __restrict__ q, const int* __restrict__ r,
                              const float* __restrict__ k_emb, const float* __restrict__ v_emb,
                              float* __restrict__ kg, float* __restrict__ vg)
{
    int row = blockIdx.x;
    int dd = threadIdx.x;
    if (dd >= D) return;
    int qi = q[row];
    int xi = qi + NQ * r[row];
    kg[(long)row*D + dd] = k_emb[(long)qi*D + dd];
    vg[(long)row*D + dd] = v_emb[(long)xi*D + dd];
}

// ---------------- w = softmax(k @ Mk^T) : one wave per row --------------------
__global__ __launch_bounds__(256) void wsoftmax_kernel(const float* __restrict__ kg,
                                                       const float* __restrict__ Mk,
                                                       float* __restrict__ w_out)
{
    int wave = (int)((blockIdx.x * (long)blockDim.x + threadIdx.x) >> 6);
    int lane = threadIdx.x & 63;
    if (wave >= BNROWS) return;
    const float* krow = kg + (long)wave * D;
    float dot = -1e30f;
    if (lane < M_SLOTS) {
        const float* mk = Mk + lane*D;
        float s = 0.f;
        for (int d = 0; d < D; d++) s += krow[d]*mk[d];
        dot = s;
    }
    float mx = dot;
    for (int off = 32; off; off >>= 1) mx = fmaxf(mx, __shfl_xor(mx, off));
    float ev = (lane < M_SLOTS) ? __expf(dot - mx) : 0.f;
    float sum = ev;
    for (int off = 32; off; off >>= 1) sum += __shfl_xor(sum, off);
    if (lane < M_SLOTS) w_out[(long)wave*M_SLOTS + lane] = ev / sum;
}

// ---------------- sequential scan over t, fused read einsum -------------------
// grid: (64 batches, 4 dd-chunks of 50), block: 64 threads (50 active)
// each thread owns one dd column: 50-element register state (all s slots)
__global__ __launch_bounds__(64) void scan_kernel(const float* __restrict__ w,
    const float* __restrict__ e, const float* __restrict__ a,
    const float* __restrict__ Mv0, float* __restrict__ Mv_out,
    float* __restrict__ read_out)
{
    int b = blockIdx.x;
    int ddc = blockIdx.y;
    int lane = threadIdx.x;
    int dd = ddc*M_SLOTS + lane;
    bool active = lane < M_SLOTS;
    __shared__ float wsh[M_SLOTS];
    float st[M_SLOTS];
    if (active) {
        #pragma unroll
        for (int s = 0; s < M_SLOTS; s++) st[s] = Mv0[s*D + dd];
    }
    for (int t = 0; t < D; t++) {
        if (lane < M_SLOTS) wsh[lane] = w[(long)(b*D + t)*M_SLOTS + lane];
        __syncthreads();
        if (active) {
            long rowoff = (long)(b*D + t)*D + dd;
            float et = e[rowoff], at = a[rowoff];
            float racc = 0.f;
            long mvbase = (long)(b*(D+1) + t)*M_SLOTS*D + dd;
            #pragma unroll
            for (int s = 0; s < M_SLOTS; s++) {
                float ss = st[s];
                Mv_out[mvbase + (long)s*D] = ss;       // emit pre-update state
                racc += ss * wsh[s];                   // fused read einsum
                st[s] = ss + wsh[s]*(at - et*ss);      // Mv*(1-we) + wa
            }
            read_out[rowoff] = racc;
        }
        __syncthreads();
    }
    if (active) {
        long mvbase = (long)(b*(D+1) + D)*M_SLOTS*D + dd;
        #pragma unroll
        for (int s = 0; s < M_SLOTS; s++) Mv_out[mvbase + (long)s*D] = st[s];
    }
}

// ---------------- p = sigmoid(f . Wp[:200] + f_l . Wp[200:] + bp) -------------
__global__ __launch_bounds__(256) void p_kernel(const float* __restrict__ f,
    const float* __restrict__ fl, const float* __restrict__ Wp,
    const float* __restrict__ bp, float* __restrict__ p_out)
{
    int b = blockIdx.x;
    int t = threadIdx.x;
    if (t >= D) return;
    float s2 = 0.f;
    for (int c = 0; c < D; c++) s2 += fl[(long)(b*D + c)*D + t] * Wp[D + c];
    float s1 = 0.f;
    const float* frow = f + (long)(b*D + t)*D;
    for (int j = 0; j < D; j++) s1 += frow[j]*Wp[j];
    float x = s1 + s2 + bp[0];
    p_out[b*D + t] = 1.f/(1.f + __expf(-x));
}

extern "C" void kernel_launch(void* const* d_in, const int* in_sizes, int n_in,
                              void* d_out, int out_size, void* d_ws, size_t ws_size,
                              hipStream_t stream) {
    const int*   q     = (const int*)  d_in[0];
    const int*   r     = (const int*)  d_in[1];
    const float* bert  = (const float*)d_in[2];
    const float* k_emb = (const float*)d_in[3];
    const float* v_emb = (const float*)d_in[4];
    const float* Mk    = (const float*)d_in[5];
    const float* Mv0   = (const float*)d_in[6];
    const float* W_at  = (const float*)d_in[7];
    const float* b_at  = (const float*)d_in[8];
    const float* W_at2 = (const float*)d_in[9];
    const float* b_at2 = (const float*)d_in[10];
    const float* W_fus = (const float*)d_in[11];
    const float* b_fus = (const float*)d_in[12];
    const float* W_e   = (const float*)d_in[13];
    const float* b_e   = (const float*)d_in[14];
    const float* W_a   = (const float*)d_in[15];
    const float* b_a   = (const float*)d_in[16];
    const float* W_f   = (const float*)d_in[17];
    const float* b_f   = (const float*)d_in[18];
    const float* W_p   = (const float*)d_in[19];
    const float* b_p   = (const float*)d_in[20];

    // outputs: p [64,200] | Mv [64,201,50,200] | w [64,200,50]
    float* out_p  = (float*)d_out;
    float* out_Mv = out_p + (long)BATCH*D;
    float* out_w  = out_Mv + (long)BATCH*(D+1)*M_SLOTS*D;

    // workspace layout (floats); em region is reused after em_at is built
    float* ws    = (float*)d_ws;
    float* em    = ws;                         // 6,553,600  [B*512, 200]
    float* em_at = ws + 6553600;               // 2,560,000  [B*200, 200]
    float* kg    = ws;                         // 2,560,000  (overlays em, used after K2)
    float* vg    = ws + 2560000;               // 2,560,000
    float* e_b   = ws + 9113600;               // 2,560,000
    float* a_b   = ws + 11673600;              // 2,560,000
    float* rd_b  = ws + 14233600;              // 2,560,000
    float* f_b   = ws + 16793600;              // 2,560,000
    float* fl_b  = ws + 19353600;              // 2,560,000  total 21,913,600 f = 87.7 MB

    // 1) em = bert @ W_at^T + b_at           [32768,200]
    gemm_nt<false,0,false><<<dim3(4,512,1),256,0,stream>>>(
        bert, W_at, b_at, em, BATCH*LBERT, D, HBERT, HBERT, HBERT, D, 0, 0);

    // 2) em_at[b] = em[b]^T @ W_at2^T + b_at2   (A is k-major: em[b,l,i])
    gemm_nt<true,0,false><<<dim3(4,4,BATCH),256,0,stream>>>(
        em, W_at2, b_at2, em_at, D, D, LBERT, D, LBERT, D,
        (long)LBERT*D, (long)D*D);

    // 3) gather k, v   (overlays em region — must come after step 2)
    gather_kernel<<<BNROWS, 256, 0, stream>>>(q, r, k_emb, v_emb, kg, vg);

    // 4) w = softmax(k @ Mk^T)  -> output region
    wsoftmax_kernel<<<BNROWS/4, 256, 0, stream>>>(kg, Mk, out_w);

    // 5) e = sigmoid(v @ W_e^T + b_e);  a = tanh(v @ W_a^T + b_a)
    gemm_nt<false,1,false><<<dim3(4,200,1),256,0,stream>>>(
        vg, W_e, b_e, e_b, BNROWS, D, D, D, D, D, 0, 0);
    gemm_nt<false,2,false><<<dim3(4,200,1),256,0,stream>>>(
        vg, W_a, b_a, a_b, BNROWS, D, D, D, D, D, 0, 0);

    // 6) scan: emit Mv (pre + last) to output, fused read einsum
    scan_kernel<<<dim3(BATCH,4),64,0,stream>>>(out_w, e_b, a_b, Mv0, out_Mv, rd_b);

    // 7) f = tanh(cat(read,k) @ W_f^T + b_f)  — two accumulating passes
    gemm_nt<false,0,false><<<dim3(4,200,1),256,0,stream>>>(
        rd_b, W_f, nullptr, f_b, BNROWS, D, D, D, 2*D, D, 0, 0);
    gemm_nt<false,2,true><<<dim3(4,200,1),256,0,stream>>>(
        kg, W_f + D, b_f, f_b, BNROWS, D, D, D, 2*D, D, 0, 0);

    // 8) f_l_pre = relu(cat(v, em_at) @ W_fus^T + b_fus)   [B*200(c), 200(j)]
    gemm_nt<false,0,false><<<dim3(4,200,1),256,0,stream>>>(
        vg, W_fus, nullptr, fl_b, BNROWS, D, D, D, 2*D, D, 0, 0);
    gemm_nt<false,3,true><<<dim3(4,200,1),256,0,stream>>>(
        em_at, W_fus + D, b_fus, fl_b, BNROWS, D, D, D, 2*D, D, 0, 0);

    // 9) p = sigmoid(f.Wp[:200] + f_l.Wp[200:] + bp)
    p_kernel<<<BATCH, 256, 0, stream>>>(f_b, fl_b, W_p, b_p, out_p);
}